// Round 1
// baseline (1786.517 us; speedup 1.0000x reference)
//
#include <hip/hip_runtime.h>
#include <hip/hip_bf16.h>
#include <math.h>

// MaskedMultiHeadAttention: B=4, L=2048, D=1024, fp32, heads never split.
// out = softmax((XQ Wq^T)(XK Wk^T)^T / 8) (XV Wv^T) Wo^T ; also return attn weights.
// d_out = [ out : 4*2048*1024 floats | attn : 4*2048*2048 floats ]
// d_ws  = qp | kp | vp  (3 * 33.55 MB = 100.7 MB); x reuses qp.

#define NT   256
#define TILE 128
#define BK   8
#define LDP  (TILE + 4)

static constexpr int B_ = 4;
static constexpr int L_ = 2048;
static constexpr int D_ = 1024;

// C[M,N] = scale * A[M,K] @ Bt[N,K]^T   (both operands row-major with K inner)
// optional causal-style mask (k <= q -> -inf), faithful to the buggy reference.
__global__ __launch_bounds__(NT) void gemm_abT_k(
    const float* __restrict__ A, const float* __restrict__ Bt, float* __restrict__ C,
    int M, int N, int K, long sA, long sB, long sC,
    float scale, int useMask, const int* __restrict__ mflag)
{
    const int b = blockIdx.z;
    A  += (long)b * sA;
    Bt += (long)b * sB;
    C  += (long)b * sC;

    __shared__ float As[BK][LDP];
    __shared__ float Bs[BK][LDP];

    const int tid = threadIdx.x;
    const int tx  = tid & 15;
    const int ty  = tid >> 4;
    const int bm  = blockIdx.y * TILE;
    const int bn  = blockIdx.x * TILE;

    // staging: each thread loads one float4 of A-tile and one of B-tile
    const int lr = tid >> 1;         // 0..127 tile row
    const int lk = (tid & 1) * 4;    // 0 or 4  (k offset)
    const float* Ap = A  + (long)(bm + lr) * K + lk;
    const float* Bp = Bt + (long)(bn + lr) * K + lk;

    float acc[8][8];
#pragma unroll
    for (int i = 0; i < 8; ++i)
#pragma unroll
        for (int j = 0; j < 8; ++j) acc[i][j] = 0.f;

    for (int k0 = 0; k0 < K; k0 += BK) {
        const float4 av = *(const float4*)(Ap + k0);
        const float4 bv = *(const float4*)(Bp + k0);
        __syncthreads();
        As[lk+0][lr] = av.x; As[lk+1][lr] = av.y; As[lk+2][lr] = av.z; As[lk+3][lr] = av.w;
        Bs[lk+0][lr] = bv.x; Bs[lk+1][lr] = bv.y; Bs[lk+2][lr] = bv.z; Bs[lk+3][lr] = bv.w;
        __syncthreads();
#pragma unroll
        for (int kk = 0; kk < BK; ++kk) {
            float a[8], bb[8];
            *(float4*)&a[0]  = *(const float4*)&As[kk][ty*4];
            *(float4*)&a[4]  = *(const float4*)&As[kk][64 + ty*4];
            *(float4*)&bb[0] = *(const float4*)&Bs[kk][tx*4];
            *(float4*)&bb[4] = *(const float4*)&Bs[kk][64 + tx*4];
#pragma unroll
            for (int i = 0; i < 8; ++i)
#pragma unroll
                for (int j = 0; j < 8; ++j)
                    acc[i][j] = fmaf(a[i], bb[j], acc[i][j]);
        }
    }

    const bool msk = (useMask != 0) && (mflag[0] != 0);
#pragma unroll
    for (int hi = 0; hi < 2; ++hi)
#pragma unroll
        for (int i = 0; i < 4; ++i) {
            const int r = bm + hi*64 + ty*4 + i;
#pragma unroll
            for (int hj = 0; hj < 2; ++hj) {
                const int c0 = bn + hj*64 + tx*4;
                float v[4];
#pragma unroll
                for (int j = 0; j < 4; ++j) v[j] = acc[hi*4+i][hj*4+j] * scale;
                if (msk) {
#pragma unroll
                    for (int j = 0; j < 4; ++j)
                        if (c0 + j <= r) v[j] = -INFINITY;
                }
                *(float4*)&C[(long)r * N + c0] = *(float4*)&v[0];
            }
        }
}

// C[M,N] = A[M,K] @ B[K,N]   (B row-major, N inner)
__global__ __launch_bounds__(NT) void gemm_ab_k(
    const float* __restrict__ A, const float* __restrict__ B, float* __restrict__ C,
    int M, int N, int K, long sA, long sB, long sC)
{
    const int b = blockIdx.z;
    A += (long)b * sA;
    B += (long)b * sB;
    C += (long)b * sC;

    __shared__ float As[BK][LDP];
    __shared__ float Bs[BK][LDP];

    const int tid = threadIdx.x;
    const int tx  = tid & 15;
    const int ty  = tid >> 4;
    const int bm  = blockIdx.y * TILE;
    const int bn  = blockIdx.x * TILE;

    const int lr = tid >> 1;        // A: 0..127 tile row
    const int lk = (tid & 1) * 4;   // A: k offset 0/4
    const int br = tid >> 5;        // B: k row 0..7
    const int bc = (tid & 31) * 4;  // B: col 0..124
    const float* Ap = A + (long)(bm + lr) * K + lk;
    const float* Bp = B + (long)br * N + bn + bc;

    float acc[8][8];
#pragma unroll
    for (int i = 0; i < 8; ++i)
#pragma unroll
        for (int j = 0; j < 8; ++j) acc[i][j] = 0.f;

    for (int k0 = 0; k0 < K; k0 += BK) {
        const float4 av = *(const float4*)(Ap + k0);
        const float4 bv = *(const float4*)(Bp + (long)k0 * N);
        __syncthreads();
        As[lk+0][lr] = av.x; As[lk+1][lr] = av.y; As[lk+2][lr] = av.z; As[lk+3][lr] = av.w;
        *(float4*)&Bs[br][bc] = bv;
        __syncthreads();
#pragma unroll
        for (int kk = 0; kk < BK; ++kk) {
            float a[8], bb[8];
            *(float4*)&a[0]  = *(const float4*)&As[kk][ty*4];
            *(float4*)&a[4]  = *(const float4*)&As[kk][64 + ty*4];
            *(float4*)&bb[0] = *(const float4*)&Bs[kk][tx*4];
            *(float4*)&bb[4] = *(const float4*)&Bs[kk][64 + tx*4];
#pragma unroll
            for (int i = 0; i < 8; ++i)
#pragma unroll
                for (int j = 0; j < 8; ++j)
                    acc[i][j] = fmaf(a[i], bb[j], acc[i][j]);
        }
    }

#pragma unroll
    for (int hi = 0; hi < 2; ++hi)
#pragma unroll
        for (int i = 0; i < 4; ++i) {
            const int r = bm + hi*64 + ty*4 + i;
#pragma unroll
            for (int hj = 0; hj < 2; ++hj) {
                const int c0 = bn + hj*64 + tx*4;
                float4 v;
                v.x = acc[hi*4+i][hj*4+0];
                v.y = acc[hi*4+i][hj*4+1];
                v.z = acc[hi*4+i][hj*4+2];
                v.w = acc[hi*4+i][hj*4+3];
                *(float4*)&C[(long)r * N + c0] = v;
            }
        }
}

// in-place row softmax over rows of length 2048; one block (256 thr) per row
__global__ __launch_bounds__(256) void softmax_rows_k(float* __restrict__ S)
{
    const long row = blockIdx.x;
    float* p = S + row * (long)L_;
    const int tid = threadIdx.x;

    float4 v0 = ((const float4*)p)[tid];
    float4 v1 = ((const float4*)p)[tid + 256];

    float m = fmaxf(fmaxf(fmaxf(v0.x, v0.y), fmaxf(v0.z, v0.w)),
                    fmaxf(fmaxf(v1.x, v1.y), fmaxf(v1.z, v1.w)));
#pragma unroll
    for (int o = 32; o > 0; o >>= 1) m = fmaxf(m, __shfl_xor(m, o, 64));

    __shared__ float wmax[4], wsum[4];
    if ((tid & 63) == 0) wmax[tid >> 6] = m;
    __syncthreads();
    m = fmaxf(fmaxf(wmax[0], wmax[1]), fmaxf(wmax[2], wmax[3]));

    v0.x = expf(v0.x - m); v0.y = expf(v0.y - m);
    v0.z = expf(v0.z - m); v0.w = expf(v0.w - m);
    v1.x = expf(v1.x - m); v1.y = expf(v1.y - m);
    v1.z = expf(v1.z - m); v1.w = expf(v1.w - m);

    float s = v0.x + v0.y + v0.z + v0.w + v1.x + v1.y + v1.z + v1.w;
#pragma unroll
    for (int o = 32; o > 0; o >>= 1) s += __shfl_xor(s, o, 64);
    if ((tid & 63) == 0) wsum[tid >> 6] = s;
    __syncthreads();
    s = wsum[0] + wsum[1] + wsum[2] + wsum[3];

    const float inv = 1.f / s;
    v0.x *= inv; v0.y *= inv; v0.z *= inv; v0.w *= inv;
    v1.x *= inv; v1.y *= inv; v1.z *= inv; v1.w *= inv;
    ((float4*)p)[tid] = v0;
    ((float4*)p)[tid + 256] = v1;
}

extern "C" void kernel_launch(void* const* d_in, const int* in_sizes, int n_in,
                              void* d_out, int out_size, void* d_ws, size_t ws_size,
                              hipStream_t stream) {
    const float* Q   = (const float*)d_in[0];
    const float* K   = (const float*)d_in[1];
    const float* V   = (const float*)d_in[2];
    const float* W_Q = (const float*)d_in[3];
    const float* W_K = (const float*)d_in[4];
    const float* W_V = (const float*)d_in[5];
    const float* W_O = (const float*)d_in[6];
    const int* masked = (const int*)d_in[7];

    float* out  = (float*)d_out;                         // [4,2048,1024]
    float* attn = out + (size_t)B_ * L_ * D_;            // [4,2048,2048]

    float* qp = (float*)d_ws;                            // [4,2048,1024]
    float* kp = qp + (size_t)B_ * L_ * D_;
    float* vp = kp + (size_t)B_ * L_ * D_;
    float* xp = qp;                                      // reuse qp after scores

    const long SLD = (long)L_ * D_;   // per-batch stride of [L,D]
    const long SLL = (long)L_ * L_;   // per-batch stride of [L,L]

    dim3 blk(NT);

    // projections: [B*L, D] @ W^T  -> M=8192, N=1024, K=1024
    dim3 gproj(D_ / TILE, (B_ * L_) / TILE, 1);
    gemm_abT_k<<<gproj, blk, 0, stream>>>(Q, W_Q, qp, B_*L_, D_, D_, 0, 0, 0, 1.f, 0, masked);
    gemm_abT_k<<<gproj, blk, 0, stream>>>(K, W_K, kp, B_*L_, D_, D_, 0, 0, 0, 1.f, 0, masked);
    gemm_abT_k<<<gproj, blk, 0, stream>>>(V, W_V, vp, B_*L_, D_, D_, 0, 0, 0, 1.f, 0, masked);

    // scores = qp @ kp^T / 8  (per batch), straight into the attn output slot
    dim3 gsc(L_ / TILE, L_ / TILE, B_);
    gemm_abT_k<<<gsc, blk, 0, stream>>>(qp, kp, attn, L_, L_, D_, SLD, SLD, SLL,
                                        0.125f, 1, masked);

    // softmax in place
    softmax_rows_k<<<dim3(B_ * L_), 256, 0, stream>>>(attn);

    // x = attn @ vp   (per batch): M=2048, N=1024, K=2048
    dim3 gav(D_ / TILE, L_ / TILE, B_);
    gemm_ab_k<<<gav, blk, 0, stream>>>(attn, vp, xp, L_, D_, L_, SLL, SLD, SLD);

    // out = x @ W_O^T : M=8192, N=1024, K=1024
    gemm_abT_k<<<gproj, blk, 0, stream>>>(xp, W_O, out, B_*L_, D_, D_, 0, 0, 0, 1.f, 0, masked);
}

// Round 4
// 370.728 us; speedup vs baseline: 4.8189x; 4.8189x over previous
//
#include <hip/hip_runtime.h>
#include <math.h>

// MaskedMultiHeadAttention (B=4, L=2048, D=1024), fp32 in/out, fp16-MFMA internals.
// d_out = [ out : 4*2048*1024 f32 | attn : 4*2048*2048 f32 ]
// ws (56MB): WQh WKh WVh WOh (f16) | qh | kh | vT (f16); x reuses qh.

static constexpr int B_ = 4;
static constexpr int L_ = 2048;
static constexpr int D_ = 1024;

#define BM 128
#define BN 128
#define BKK 64   // K-step in elements (fp16)

typedef _Float16 f16x8 __attribute__((ext_vector_type(8)));
typedef float    f32x4 __attribute__((ext_vector_type(4)));
typedef short    s16x8 __attribute__((ext_vector_type(8)));
typedef unsigned short u16x4 __attribute__((ext_vector_type(4)));

typedef __attribute__((address_space(1))) const unsigned int GU32;
typedef __attribute__((address_space(3))) unsigned int LU32;

__device__ __forceinline__ void gload_lds16(const void* g, void* l) {
    __builtin_amdgcn_global_load_lds((GU32*)g, (LU32*)l, 16, 0, 0);
}

__device__ __forceinline__ short f2h_bits(float x) {
    union { _Float16 h; short s; } u;
    u.h = (_Float16)x;
    return u.s;
}

__device__ __forceinline__ s16x8 cvt8h(float4 a, float4 b) {
    union { _Float16 h[8]; s16x8 s; } u;
    u.h[0] = (_Float16)a.x; u.h[1] = (_Float16)a.y;
    u.h[2] = (_Float16)a.z; u.h[3] = (_Float16)a.w;
    u.h[4] = (_Float16)b.x; u.h[5] = (_Float16)b.y;
    u.h[6] = (_Float16)b.z; u.h[7] = (_Float16)b.w;
    return u.s;
}

// C[M,N](+batch) = scale * A[M,K] @ Bt[N,K]^T, fp16 MFMA, fp32 accum.
// AF32: A operand is fp32 (reg-staged + converted); else fp16 via global_load_lds.
// OMODE: 0 = store f16 row-major [M,N]; 1 = store f16 transposed (vT: [b][N][L_]);
//        2 = store f32 with scale (+ optional faithful-buggy tril mask).
template<int AF32, int OMODE>
__global__ __launch_bounds__(256) void hgemm(
    const void* __restrict__ Ap_, const short* __restrict__ Btp, void* __restrict__ Cp_,
    int M, int N, int K, long sA, long sB, long sC,
    float scale, int useMask, const int* __restrict__ mflag)
{
    __shared__ short As[BM * BKK];  // 16 KB
    __shared__ short Bs[BN * BKK];  // 16 KB

    const int t    = threadIdx.x;
    const int wid  = t >> 6;
    const int lane = t & 63;
    const int bz   = blockIdx.z;
    const int bm   = blockIdx.y * BM;
    const int bn   = blockIdx.x * BN;

    const short* Bt = Btp + (long)bz * sB;
    const float* A32 = (const float*)Ap_ + (AF32 ? (long)bz * sA : 0);
    const short* A16 = (const short*)Ap_ + (AF32 ? 0 : (long)bz * sA);

    const int wr = wid >> 1, wc = wid & 1;   // wave 2x2 grid, each 64x64
    const int lr = lane & 15, lk = lane >> 4;

    const int srow  = t >> 3;  // staging row-in-issue (0..31)
    const int sslot = t & 7;   // staging 16B slot (0..7)

    f32x4 acc[4][4];
#pragma unroll
    for (int m = 0; m < 4; ++m)
#pragma unroll
        for (int n = 0; n < 4; ++n) acc[m][n] = (f32x4)0.f;

    for (int k0 = 0; k0 < K; k0 += BKK) {
        __syncthreads();
        // ---- stage B tile (always fp16, global_load_lds, pre-swizzled source) ----
#pragma unroll
        for (int i = 0; i < 4; ++i) {
            const int rb = i * 32 + srow;
            const short* g = Bt + (long)(bn + rb) * K + k0 + ((sslot ^ (rb & 7)) << 3);
            gload_lds16(g, &Bs[i * 2048 + wid * 512]);
        }
        // ---- stage A tile ----
        if constexpr (AF32) {
            const int r = t >> 1, h = t & 1;      // row 0..127, half-row
            const float* ga = A32 + (long)(bm + r) * K + k0 + h * 32;
            float4 f[8];
#pragma unroll
            for (int j = 0; j < 8; ++j) f[j] = ((const float4*)ga)[j];
#pragma unroll
            for (int q = 0; q < 4; ++q)
                *(s16x8*)&As[r * 64 + ((((h << 2) + q) ^ (r & 7)) << 3)] =
                    cvt8h(f[2 * q], f[2 * q + 1]);
        } else {
#pragma unroll
            for (int i = 0; i < 4; ++i) {
                const int ra = i * 32 + srow;
                const short* g = A16 + (long)(bm + ra) * K + k0 + ((sslot ^ (ra & 7)) << 3);
                gload_lds16(g, &As[i * 2048 + wid * 512]);
            }
        }
        __syncthreads();
        // ---- compute: 2 k-subtiles x 16 MFMA ----
#pragma unroll
        for (int kk = 0; kk < 2; ++kk) {
            const int slotk = kk * 4 + lk;
            f16x8 a[4], b[4];
#pragma unroll
            for (int m = 0; m < 4; ++m) {
                const int r = wr * 64 + m * 16 + lr;
                a[m] = *(const f16x8*)&As[r * 64 + ((slotk ^ (r & 7)) << 3)];
            }
#pragma unroll
            for (int n = 0; n < 4; ++n) {
                const int c = wc * 64 + n * 16 + lr;
                b[n] = *(const f16x8*)&Bs[c * 64 + ((slotk ^ (c & 7)) << 3)];
            }
#pragma unroll
            for (int m = 0; m < 4; ++m)
#pragma unroll
                for (int n = 0; n < 4; ++n)
                    acc[m][n] = __builtin_amdgcn_mfma_f32_16x16x32_f16(a[m], b[n], acc[m][n], 0, 0, 0);
        }
    }

    // ---- epilogue ----
    if constexpr (OMODE == 2) {
        float* C = (float*)Cp_ + (long)bz * sC;
        const bool msk = useMask && (mflag[0] != 0);
#pragma unroll
        for (int m = 0; m < 4; ++m) {
            const int r0 = bm + wr * 64 + m * 16 + lk * 4;
#pragma unroll
            for (int n = 0; n < 4; ++n) {
                const int c = bn + wc * 64 + n * 16 + lr;
#pragma unroll
                for (int g = 0; g < 4; ++g) {
                    float v = acc[m][n][g] * scale;
                    if (msk && c <= r0 + g) v = -INFINITY;
                    C[(long)(r0 + g) * N + c] = v;
                }
            }
        }
    } else if constexpr (OMODE == 0) {
        short* C = (short*)Cp_ + (long)bz * sC;
#pragma unroll
        for (int m = 0; m < 4; ++m) {
            const int r0 = bm + wr * 64 + m * 16 + lk * 4;
#pragma unroll
            for (int n = 0; n < 4; ++n) {
                const int c = bn + wc * 64 + n * 16 + lr;
#pragma unroll
                for (int g = 0; g < 4; ++g)
                    C[(long)(r0 + g) * N + c] = f2h_bits(acc[m][n][g]);
            }
        }
    } else {  // OMODE == 1: vT[b][N][L_], batch from global row
        short* C = (short*)Cp_;
#pragma unroll
        for (int m = 0; m < 4; ++m) {
            const int rg = bm + wr * 64 + m * 16 + lk * 4;
            const long rb = (long)(rg >> 11) * ((long)N * L_) + (rg & (L_ - 1));
#pragma unroll
            for (int n = 0; n < 4; ++n) {
                const int c = bn + wc * 64 + n * 16 + lr;
                u16x4 v;
#pragma unroll
                for (int g = 0; g < 4; ++g) v[g] = (unsigned short)f2h_bits(acc[m][n][g]);
                *(u16x4*)&C[rb + (long)c * L_] = v;
            }
        }
    }
}

// fp32 -> fp16 bit pattern, 8 elems/thread
__global__ __launch_bounds__(256) void cvt_f32_f16_k(
    const float* __restrict__ in, short* __restrict__ out, int n8)
{
    int i = blockIdx.x * 256 + threadIdx.x;
    if (i < n8) {
        float4 a = ((const float4*)in)[2 * i];
        float4 b = ((const float4*)in)[2 * i + 1];
        *(s16x8*)&out[i * 8] = cvt8h(a, b);
    }
}

// in-place row softmax over rows of length 2048; one block (256 thr) per row
__global__ __launch_bounds__(256) void softmax_rows_k(float* __restrict__ S)
{
    const long row = blockIdx.x;
    float* p = S + row * (long)L_;
    const int tid = threadIdx.x;

    float4 v0 = ((const float4*)p)[tid];
    float4 v1 = ((const float4*)p)[tid + 256];

    float m = fmaxf(fmaxf(fmaxf(v0.x, v0.y), fmaxf(v0.z, v0.w)),
                    fmaxf(fmaxf(v1.x, v1.y), fmaxf(v1.z, v1.w)));
#pragma unroll
    for (int o = 32; o > 0; o >>= 1) m = fmaxf(m, __shfl_xor(m, o, 64));

    __shared__ float wmax[4], wsum[4];
    if ((tid & 63) == 0) wmax[tid >> 6] = m;
    __syncthreads();
    m = fmaxf(fmaxf(wmax[0], wmax[1]), fmaxf(wmax[2], wmax[3]));

    v0.x = expf(v0.x - m); v0.y = expf(v0.y - m);
    v0.z = expf(v0.z - m); v0.w = expf(v0.w - m);
    v1.x = expf(v1.x - m); v1.y = expf(v1.y - m);
    v1.z = expf(v1.z - m); v1.w = expf(v1.w - m);

    float s = v0.x + v0.y + v0.z + v0.w + v1.x + v1.y + v1.z + v1.w;
#pragma unroll
    for (int o = 32; o > 0; o >>= 1) s += __shfl_xor(s, o, 64);
    if ((tid & 63) == 0) wsum[tid >> 6] = s;
    __syncthreads();
    s = wsum[0] + wsum[1] + wsum[2] + wsum[3];

    const float inv = 1.f / s;
    v0.x *= inv; v0.y *= inv; v0.z *= inv; v0.w *= inv;
    v1.x *= inv; v1.y *= inv; v1.z *= inv; v1.w *= inv;
    ((float4*)p)[tid] = v0;
    ((float4*)p)[tid + 256] = v1;
}

extern "C" void kernel_launch(void* const* d_in, const int* in_sizes, int n_in,
                              void* d_out, int out_size, void* d_ws, size_t ws_size,
                              hipStream_t stream) {
    const float* Q   = (const float*)d_in[0];
    const float* K   = (const float*)d_in[1];
    const float* V   = (const float*)d_in[2];
    const float* W_Q = (const float*)d_in[3];
    const float* W_K = (const float*)d_in[4];
    const float* W_V = (const float*)d_in[5];
    const float* W_O = (const float*)d_in[6];
    const int* masked = (const int*)d_in[7];

    float* out  = (float*)d_out;                    // [4,2048,1024]
    float* attn = out + (size_t)B_ * L_ * D_;       // [4,2048,2048]

    // ws layout (shorts)
    short* wq = (short*)d_ws;                       // 1M each
    short* wk = wq + (size_t)D_ * D_;
    short* wv = wk + (size_t)D_ * D_;
    short* wo = wv + (size_t)D_ * D_;
    short* qh = wo + (size_t)D_ * D_;               // [8192,1024] f16
    short* kh = qh + (size_t)B_ * L_ * D_;
    short* vT = kh + (size_t)B_ * L_ * D_;          // [4][1024][2048] f16
    short* xh = qh;                                 // reuse after scores

    const long SLD = (long)L_ * D_;
    const long SLL = (long)L_ * L_;

    // 1) weights fp32 -> fp16
    const int n8 = D_ * D_ / 8;
    cvt_f32_f16_k<<<dim3(n8 / 256), 256, 0, stream>>>(W_Q, wq, n8);
    cvt_f32_f16_k<<<dim3(n8 / 256), 256, 0, stream>>>(W_K, wk, n8);
    cvt_f32_f16_k<<<dim3(n8 / 256), 256, 0, stream>>>(W_V, wv, n8);
    cvt_f32_f16_k<<<dim3(n8 / 256), 256, 0, stream>>>(W_O, wo, n8);

    // 2) projections (A = fp32 inputs, reg-staged convert)
    dim3 gproj(D_ / BN, (B_ * L_) / BM, 1);
    hgemm<1, 0><<<gproj, 256, 0, stream>>>(Q, wq, qh, B_ * L_, D_, D_, 0, 0, 0, 1.f, 0, masked);
    hgemm<1, 0><<<gproj, 256, 0, stream>>>(K, wk, kh, B_ * L_, D_, D_, 0, 0, 0, 1.f, 0, masked);
    hgemm<1, 1><<<gproj, 256, 0, stream>>>(V, wv, vT, B_ * L_, D_, D_, 0, 0, 0, 1.f, 0, masked);

    // 3) scores = q @ k^T / 8 -> fp32 into attn slot (+ faithful mask)
    dim3 gsc(L_ / BN, L_ / BM, B_);
    hgemm<0, 2><<<gsc, 256, 0, stream>>>(qh, kh, attn, L_, L_, D_, SLD, SLD, SLL,
                                         0.125f, 1, masked);

    // 4) softmax rows, in place (fp32)
    softmax_rows_k<<<dim3(B_ * L_), 256, 0, stream>>>(attn);

    // 5) x = attn @ v  (A = fp32 attn reg-staged; B = vT) -> f16 x
    dim3 gav(D_ / BN, L_ / BM, B_);
    hgemm<1, 0><<<gav, 256, 0, stream>>>(attn, vT, xh, L_, D_, L_, SLL, SLD, SLD,
                                         1.f, 0, masked);

    // 6) out = x @ W_O^T -> fp32
    hgemm<0, 2><<<gproj, 256, 0, stream>>>(xh, wo, out, B_ * L_, D_, D_, 0, 0, 0,
                                           1.f, 0, masked);
}

// Round 5
// 339.371 us; speedup vs baseline: 5.2642x; 1.0924x over previous
//
#include <hip/hip_runtime.h>
#include <math.h>

// MaskedMultiHeadAttention (B=4, L=2048, D=1024), fp32 in/out, fp16-MFMA internals.
// d_out = [ out : 4*2048*1024 f32 | attn : 4*2048*2048 f32 ]
// ws (92MB): WQh WKh WVh WOh (f16) | qh | kh | vT | attn16 (f16); x reuses qh.

static constexpr int B_ = 4;
static constexpr int L_ = 2048;
static constexpr int D_ = 1024;

#define BM 128
#define BN 128
#define BKK 64   // K-step in elements (fp16)

typedef _Float16 f16x8 __attribute__((ext_vector_type(8)));
typedef float    f32x4 __attribute__((ext_vector_type(4)));
typedef short    s16x8 __attribute__((ext_vector_type(8)));
typedef unsigned short u16x4 __attribute__((ext_vector_type(4)));

typedef __attribute__((address_space(1))) const unsigned int GU32;
typedef __attribute__((address_space(3))) unsigned int LU32;

__device__ __forceinline__ void gload_lds16(const void* g, void* l) {
    __builtin_amdgcn_global_load_lds((GU32*)g, (LU32*)l, 16, 0, 0);
}

__device__ __forceinline__ short f2h_bits(float x) {
    union { _Float16 h; short s; } u;
    u.h = (_Float16)x;
    return u.s;
}

__device__ __forceinline__ s16x8 cvt8h(float4 a, float4 b) {
    union { _Float16 h[8]; s16x8 s; } u;
    u.h[0] = (_Float16)a.x; u.h[1] = (_Float16)a.y;
    u.h[2] = (_Float16)a.z; u.h[3] = (_Float16)a.w;
    u.h[4] = (_Float16)b.x; u.h[5] = (_Float16)b.y;
    u.h[6] = (_Float16)b.z; u.h[7] = (_Float16)b.w;
    return u.s;
}

// C[M,N](+batch) = scale * A[M,K] @ Bt[N,K]^T, fp16 MFMA, fp32 accum.
// AF32: A operand is fp32 (reg-staged + converted); else fp16 via global_load_lds.
// OMODE: 0 = store f16 row-major [M,N]; 1 = store f16 transposed (vT: [b][N][L_]);
//        2 = store f32 with scale (+ optional faithful-buggy tril mask).
template<int AF32, int OMODE>
__global__ __launch_bounds__(256) void hgemm(
    const void* __restrict__ Ap_, const short* __restrict__ Btp, void* __restrict__ Cp_,
    int M, int N, int K, long sA, long sB, long sC,
    float scale, int useMask, const int* __restrict__ mflag)
{
    __shared__ short As[BM * BKK];  // 16 KB
    __shared__ short Bs[BN * BKK];  // 16 KB

    const int t    = threadIdx.x;
    const int wid  = t >> 6;
    const int lane = t & 63;
    const int bz   = blockIdx.z;
    const int bm   = blockIdx.y * BM;
    const int bn   = blockIdx.x * BN;

    const short* Bt = Btp + (long)bz * sB;
    const float* A32 = (const float*)Ap_ + (AF32 ? (long)bz * sA : 0);
    const short* A16 = (const short*)Ap_ + (AF32 ? 0 : (long)bz * sA);

    const int wr = wid >> 1, wc = wid & 1;   // wave 2x2 grid, each 64x64
    const int lr = lane & 15, lk = lane >> 4;

    const int srow  = t >> 3;  // staging row-in-issue (0..31)
    const int sslot = t & 7;   // staging 16B slot (0..7)

    f32x4 acc[4][4];
#pragma unroll
    for (int m = 0; m < 4; ++m)
#pragma unroll
        for (int n = 0; n < 4; ++n) acc[m][n] = (f32x4)0.f;

    for (int k0 = 0; k0 < K; k0 += BKK) {
        __syncthreads();
        // ---- stage B tile (always fp16, global_load_lds, pre-swizzled source) ----
#pragma unroll
        for (int i = 0; i < 4; ++i) {
            const int rb = i * 32 + srow;
            const short* g = Bt + (long)(bn + rb) * K + k0 + ((sslot ^ (rb & 7)) << 3);
            gload_lds16(g, &Bs[i * 2048 + wid * 512]);
        }
        // ---- stage A tile ----
        if constexpr (AF32) {
            const int r = t >> 1, h = t & 1;      // row 0..127, half-row
            const float* ga = A32 + (long)(bm + r) * K + k0 + h * 32;
            float4 f[8];
#pragma unroll
            for (int j = 0; j < 8; ++j) f[j] = ((const float4*)ga)[j];
#pragma unroll
            for (int q = 0; q < 4; ++q)
                *(s16x8*)&As[r * 64 + ((((h << 2) + q) ^ (r & 7)) << 3)] =
                    cvt8h(f[2 * q], f[2 * q + 1]);
        } else {
#pragma unroll
            for (int i = 0; i < 4; ++i) {
                const int ra = i * 32 + srow;
                const short* g = A16 + (long)(bm + ra) * K + k0 + ((sslot ^ (ra & 7)) << 3);
                gload_lds16(g, &As[i * 2048 + wid * 512]);
            }
        }
        __syncthreads();
        // ---- compute: 2 k-subtiles x 16 MFMA ----
#pragma unroll
        for (int kk = 0; kk < 2; ++kk) {
            const int slotk = kk * 4 + lk;
            f16x8 a[4], b[4];
#pragma unroll
            for (int m = 0; m < 4; ++m) {
                const int r = wr * 64 + m * 16 + lr;
                a[m] = *(const f16x8*)&As[r * 64 + ((slotk ^ (r & 7)) << 3)];
            }
#pragma unroll
            for (int n = 0; n < 4; ++n) {
                const int c = wc * 64 + n * 16 + lr;
                b[n] = *(const f16x8*)&Bs[c * 64 + ((slotk ^ (c & 7)) << 3)];
            }
#pragma unroll
            for (int m = 0; m < 4; ++m)
#pragma unroll
                for (int n = 0; n < 4; ++n)
                    acc[m][n] = __builtin_amdgcn_mfma_f32_16x16x32_f16(a[m], b[n], acc[m][n], 0, 0, 0);
        }
    }

    // ---- epilogue ----
    if constexpr (OMODE == 2) {
        float* C = (float*)Cp_ + (long)bz * sC;
        const bool msk = useMask && (mflag[0] != 0);
#pragma unroll
        for (int m = 0; m < 4; ++m) {
            const int r0 = bm + wr * 64 + m * 16 + lk * 4;
#pragma unroll
            for (int n = 0; n < 4; ++n) {
                const int c = bn + wc * 64 + n * 16 + lr;
#pragma unroll
                for (int g = 0; g < 4; ++g) {
                    float v = acc[m][n][g] * scale;
                    if (msk && c <= r0 + g) v = -INFINITY;
                    C[(long)(r0 + g) * N + c] = v;
                }
            }
        }
    } else if constexpr (OMODE == 0) {
        short* C = (short*)Cp_ + (long)bz * sC;
#pragma unroll
        for (int m = 0; m < 4; ++m) {
            const int r0 = bm + wr * 64 + m * 16 + lk * 4;
#pragma unroll
            for (int n = 0; n < 4; ++n) {
                const int c = bn + wc * 64 + n * 16 + lr;
#pragma unroll
                for (int g = 0; g < 4; ++g)
                    C[(long)(r0 + g) * N + c] = f2h_bits(acc[m][n][g]);
            }
        }
    } else {  // OMODE == 1: vT[b][N][L_], batch from global row
        short* C = (short*)Cp_;
#pragma unroll
        for (int m = 0; m < 4; ++m) {
            const int rg = bm + wr * 64 + m * 16 + lk * 4;
            const long rb = (long)(rg >> 11) * ((long)N * L_) + (rg & (L_ - 1));
#pragma unroll
            for (int n = 0; n < 4; ++n) {
                const int c = bn + wc * 64 + n * 16 + lr;
                u16x4 v;
#pragma unroll
                for (int g = 0; g < 4; ++g) v[g] = (unsigned short)f2h_bits(acc[m][n][g]);
                *(u16x4*)&C[rb + (long)c * L_] = v;
            }
        }
    }
}

// fp32 -> fp16 bit pattern, 8 elems/thread
__global__ __launch_bounds__(256) void cvt_f32_f16_k(
    const float* __restrict__ in, short* __restrict__ out, int n8)
{
    int i = blockIdx.x * 256 + threadIdx.x;
    if (i < n8) {
        float4 a = ((const float4*)in)[2 * i];
        float4 b = ((const float4*)in)[2 * i + 1];
        *(s16x8*)&out[i * 8] = cvt8h(a, b);
    }
}

// in-place row softmax over rows of length 2048; one block (256 thr) per row.
// Also writes a normalized fp16 copy (for the PV GEMM's gload_lds A-path).
__global__ __launch_bounds__(256) void softmax_rows_k(
    float* __restrict__ S, short* __restrict__ S16)
{
    const long row = blockIdx.x;
    float* p = S + row * (long)L_;
    short* p16 = S16 + row * (long)L_;
    const int tid = threadIdx.x;

    float4 v0 = ((const float4*)p)[tid];
    float4 v1 = ((const float4*)p)[tid + 256];

    float m = fmaxf(fmaxf(fmaxf(v0.x, v0.y), fmaxf(v0.z, v0.w)),
                    fmaxf(fmaxf(v1.x, v1.y), fmaxf(v1.z, v1.w)));
#pragma unroll
    for (int o = 32; o > 0; o >>= 1) m = fmaxf(m, __shfl_xor(m, o, 64));

    __shared__ float wmax[4], wsum[4];
    if ((tid & 63) == 0) wmax[tid >> 6] = m;
    __syncthreads();
    m = fmaxf(fmaxf(wmax[0], wmax[1]), fmaxf(wmax[2], wmax[3]));

    v0.x = expf(v0.x - m); v0.y = expf(v0.y - m);
    v0.z = expf(v0.z - m); v0.w = expf(v0.w - m);
    v1.x = expf(v1.x - m); v1.y = expf(v1.y - m);
    v1.z = expf(v1.z - m); v1.w = expf(v1.w - m);

    float s = v0.x + v0.y + v0.z + v0.w + v1.x + v1.y + v1.z + v1.w;
#pragma unroll
    for (int o = 32; o > 0; o >>= 1) s += __shfl_xor(s, o, 64);
    if ((tid & 63) == 0) wsum[tid >> 6] = s;
    __syncthreads();
    s = wsum[0] + wsum[1] + wsum[2] + wsum[3];

    const float inv = 1.f / s;
    v0.x *= inv; v0.y *= inv; v0.z *= inv; v0.w *= inv;
    v1.x *= inv; v1.y *= inv; v1.z *= inv; v1.w *= inv;
    ((float4*)p)[tid] = v0;
    ((float4*)p)[tid + 256] = v1;

    union { _Float16 h[4]; u16x4 u; } h0, h1;
    h0.h[0] = (_Float16)v0.x; h0.h[1] = (_Float16)v0.y;
    h0.h[2] = (_Float16)v0.z; h0.h[3] = (_Float16)v0.w;
    h1.h[0] = (_Float16)v1.x; h1.h[1] = (_Float16)v1.y;
    h1.h[2] = (_Float16)v1.z; h1.h[3] = (_Float16)v1.w;
    ((u16x4*)p16)[tid] = h0.u;
    ((u16x4*)p16)[tid + 256] = h1.u;
}

extern "C" void kernel_launch(void* const* d_in, const int* in_sizes, int n_in,
                              void* d_out, int out_size, void* d_ws, size_t ws_size,
                              hipStream_t stream) {
    const float* Q   = (const float*)d_in[0];
    const float* K   = (const float*)d_in[1];
    const float* V   = (const float*)d_in[2];
    const float* W_Q = (const float*)d_in[3];
    const float* W_K = (const float*)d_in[4];
    const float* W_V = (const float*)d_in[5];
    const float* W_O = (const float*)d_in[6];
    const int* masked = (const int*)d_in[7];

    float* out  = (float*)d_out;                    // [4,2048,1024]
    float* attn = out + (size_t)B_ * L_ * D_;       // [4,2048,2048]

    // ws layout (shorts): 8MB weights | qh 16.8 | kh 16.8 | vT 16.8 | attn16 33.6
    short* wq = (short*)d_ws;
    short* wk = wq + (size_t)D_ * D_;
    short* wv = wk + (size_t)D_ * D_;
    short* wo = wv + (size_t)D_ * D_;
    short* qh = wo + (size_t)D_ * D_;               // [8192,1024] f16
    short* kh = qh + (size_t)B_ * L_ * D_;
    short* vT = kh + (size_t)B_ * L_ * D_;          // [4][1024][2048] f16
    short* attn16 = vT + (size_t)B_ * L_ * D_;      // [4][2048][2048] f16
    short* xh = qh;                                 // reuse after scores

    const long SLD = (long)L_ * D_;
    const long SLL = (long)L_ * L_;

    // 1) weights fp32 -> fp16
    const int n8 = D_ * D_ / 8;
    cvt_f32_f16_k<<<dim3(n8 / 256), 256, 0, stream>>>(W_Q, wq, n8);
    cvt_f32_f16_k<<<dim3(n8 / 256), 256, 0, stream>>>(W_K, wk, n8);
    cvt_f32_f16_k<<<dim3(n8 / 256), 256, 0, stream>>>(W_V, wv, n8);
    cvt_f32_f16_k<<<dim3(n8 / 256), 256, 0, stream>>>(W_O, wo, n8);

    // 2) projections (A = fp32 inputs, reg-staged convert)
    dim3 gproj(D_ / BN, (B_ * L_) / BM, 1);
    hgemm<1, 0><<<gproj, 256, 0, stream>>>(Q, wq, qh, B_ * L_, D_, D_, 0, 0, 0, 1.f, 0, masked);
    hgemm<1, 0><<<gproj, 256, 0, stream>>>(K, wk, kh, B_ * L_, D_, D_, 0, 0, 0, 1.f, 0, masked);
    hgemm<1, 1><<<gproj, 256, 0, stream>>>(V, wv, vT, B_ * L_, D_, D_, 0, 0, 0, 1.f, 0, masked);

    // 3) scores = q @ k^T / 8 -> fp32 into attn slot (+ faithful mask)
    dim3 gsc(L_ / BN, L_ / BM, B_);
    hgemm<0, 2><<<gsc, 256, 0, stream>>>(qh, kh, attn, L_, L_, D_, SLD, SLD, SLL,
                                         0.125f, 1, masked);

    // 4) softmax rows, in place (fp32) + fp16 copy for PV
    softmax_rows_k<<<dim3(B_ * L_), 256, 0, stream>>>(attn, attn16);

    // 5) x = attn16 @ v  (A fp16 via gload_lds; B = vT) -> f16 x
    dim3 gav(D_ / BN, L_ / BM, B_);
    hgemm<0, 0><<<gav, 256, 0, stream>>>(attn16, vT, xh, L_, D_, L_, SLL, SLD, SLD,
                                         1.f, 0, masked);

    // 6) out = x @ W_O^T -> fp32
    hgemm<0, 2><<<gproj, 256, 0, stream>>>(xh, wo, out, B_ * L_, D_, D_, 0, 0, 0,
                                           1.f, 0, masked);
}

// Round 6
// 309.408 us; speedup vs baseline: 5.7740x; 1.0968x over previous
//
#include <hip/hip_runtime.h>
#include <math.h>

// MaskedMultiHeadAttention (B=4, L=2048, D=1024), fp32 in/out, fp16-MFMA internals.
// d_out = [ out : 4*2048*1024 f32 | attn : 4*2048*2048 f32 ]
// ws (92MB): WQh WKh WVh WOh (f16) | qh | kh | vT | attn16 (f16); x reuses qh.

static constexpr int B_ = 4;
static constexpr int L_ = 2048;
static constexpr int D_ = 1024;

#define BM 128
#define BN 128
#define BKK 64   // K-step in elements (fp16)

typedef _Float16 f16x8 __attribute__((ext_vector_type(8)));
typedef float    f32x4 __attribute__((ext_vector_type(4)));
typedef short    s16x8 __attribute__((ext_vector_type(8)));
typedef unsigned short u16x4 __attribute__((ext_vector_type(4)));

typedef __attribute__((address_space(1))) const unsigned int GU32;
typedef __attribute__((address_space(3))) unsigned int LU32;

__device__ __forceinline__ void gload_lds16(const void* g, void* l) {
    __builtin_amdgcn_global_load_lds((GU32*)g, (LU32*)l, 16, 0, 0);
}

__device__ __forceinline__ short f2h_bits(float x) {
    union { _Float16 h; short s; } u;
    u.h = (_Float16)x;
    return u.s;
}

__device__ __forceinline__ s16x8 cvt8h(float4 a, float4 b) {
    union { _Float16 h[8]; s16x8 s; } u;
    u.h[0] = (_Float16)a.x; u.h[1] = (_Float16)a.y;
    u.h[2] = (_Float16)a.z; u.h[3] = (_Float16)a.w;
    u.h[4] = (_Float16)b.x; u.h[5] = (_Float16)b.y;
    u.h[6] = (_Float16)b.z; u.h[7] = (_Float16)b.w;
    return u.s;
}

// C[M,N](+batch) = scale * A[M,K] @ Bt[N,K]^T, fp16 MFMA, fp32 accum.
// AF32: A operand is fp32 (reg-staged + converted); else fp16 via global_load_lds.
// OMODE: 0 = store f16 row-major [M,N]; 1 = store f16 transposed (vT: [b][N][L_]);
//        2 = store f32 with scale (+ optional faithful-buggy tril mask).
// XCD-affinity swizzle: hw linear wg = by*gx+bx round-robins XCD = wg%8.
// Remap bx'=wg/gy, by'=wg%gy: with gy%8==0, all blocks sharing A-panel by'
// satisfy wg%8 == by'%8 -> same XCD -> A-panel fetched once into that L2.
template<int AF32, int OMODE>
__global__ __launch_bounds__(256) void hgemm(
    const void* __restrict__ Ap_, const short* __restrict__ Btp, void* __restrict__ Cp_,
    int M, int N, int K, long sA, long sB, long sC,
    float scale, int useMask, const int* __restrict__ mflag)
{
    __shared__ short As[BM * BKK];  // 16 KB
    __shared__ short Bs[BN * BKK];  // 16 KB

    const int t    = threadIdx.x;
    const int wid  = t >> 6;
    const int lane = t & 63;
    const int bz   = blockIdx.z;

    const int gx = gridDim.x, gy = gridDim.y;
    const int wg = blockIdx.y * gx + blockIdx.x;
    const int bm = (wg % gy) * BM;   // A-panel: fixed XCD
    const int bn = (wg / gy) * BN;

    const short* Bt = Btp + (long)bz * sB;
    const float* A32 = (const float*)Ap_ + (AF32 ? (long)bz * sA : 0);
    const short* A16 = (const short*)Ap_ + (AF32 ? 0 : (long)bz * sA);

    const int wr = wid >> 1, wc = wid & 1;   // wave 2x2 grid, each 64x64
    const int lr = lane & 15, lk = lane >> 4;

    const int srow  = t >> 3;  // staging row-in-issue (0..31)
    const int sslot = t & 7;   // staging 16B slot (0..7)

    f32x4 acc[4][4];
#pragma unroll
    for (int m = 0; m < 4; ++m)
#pragma unroll
        for (int n = 0; n < 4; ++n) acc[m][n] = (f32x4)0.f;

    for (int k0 = 0; k0 < K; k0 += BKK) {
        __syncthreads();
        // ---- stage B tile (always fp16, global_load_lds, pre-swizzled source) ----
#pragma unroll
        for (int i = 0; i < 4; ++i) {
            const int rb = i * 32 + srow;
            const short* g = Bt + (long)(bn + rb) * K + k0 + ((sslot ^ (rb & 7)) << 3);
            gload_lds16(g, &Bs[i * 2048 + wid * 512]);
        }
        // ---- stage A tile ----
        if constexpr (AF32) {
            const int r = t >> 1, h = t & 1;      // row 0..127, half-row
            const float* ga = A32 + (long)(bm + r) * K + k0 + h * 32;
            float4 f[8];
#pragma unroll
            for (int j = 0; j < 8; ++j) f[j] = ((const float4*)ga)[j];
#pragma unroll
            for (int q = 0; q < 4; ++q)
                *(s16x8*)&As[r * 64 + ((((h << 2) + q) ^ (r & 7)) << 3)] =
                    cvt8h(f[2 * q], f[2 * q + 1]);
        } else {
#pragma unroll
            for (int i = 0; i < 4; ++i) {
                const int ra = i * 32 + srow;
                const short* g = A16 + (long)(bm + ra) * K + k0 + ((sslot ^ (ra & 7)) << 3);
                gload_lds16(g, &As[i * 2048 + wid * 512]);
            }
        }
        __syncthreads();
        // ---- compute: 2 k-subtiles x 16 MFMA ----
#pragma unroll
        for (int kk = 0; kk < 2; ++kk) {
            const int slotk = kk * 4 + lk;
            f16x8 a[4], b[4];
#pragma unroll
            for (int m = 0; m < 4; ++m) {
                const int r = wr * 64 + m * 16 + lr;
                a[m] = *(const f16x8*)&As[r * 64 + ((slotk ^ (r & 7)) << 3)];
            }
#pragma unroll
            for (int n = 0; n < 4; ++n) {
                const int c = wc * 64 + n * 16 + lr;
                b[n] = *(const f16x8*)&Bs[c * 64 + ((slotk ^ (c & 7)) << 3)];
            }
#pragma unroll
            for (int m = 0; m < 4; ++m)
#pragma unroll
                for (int n = 0; n < 4; ++n)
                    acc[m][n] = __builtin_amdgcn_mfma_f32_16x16x32_f16(a[m], b[n], acc[m][n], 0, 0, 0);
        }
    }

    // ---- epilogue ----
    if constexpr (OMODE == 2) {
        float* C = (float*)Cp_ + (long)bz * sC;
        const bool msk = useMask && (mflag[0] != 0);
#pragma unroll
        for (int m = 0; m < 4; ++m) {
            const int r0 = bm + wr * 64 + m * 16 + lk * 4;
#pragma unroll
            for (int n = 0; n < 4; ++n) {
                const int c = bn + wc * 64 + n * 16 + lr;
#pragma unroll
                for (int g = 0; g < 4; ++g) {
                    float v = acc[m][n][g] * scale;
                    if (msk && c <= r0 + g) v = -INFINITY;
                    C[(long)(r0 + g) * N + c] = v;
                }
            }
        }
    } else if constexpr (OMODE == 0) {
        short* C = (short*)Cp_ + (long)bz * sC;
#pragma unroll
        for (int m = 0; m < 4; ++m) {
            const int r0 = bm + wr * 64 + m * 16 + lk * 4;
#pragma unroll
            for (int n = 0; n < 4; ++n) {
                const int c = bn + wc * 64 + n * 16 + lr;
#pragma unroll
                for (int g = 0; g < 4; ++g)
                    C[(long)(r0 + g) * N + c] = f2h_bits(acc[m][n][g]);
            }
        }
    } else {  // OMODE == 1: vT[b][N][L_], batch from global row
        short* C = (short*)Cp_;
#pragma unroll
        for (int m = 0; m < 4; ++m) {
            const int rg = bm + wr * 64 + m * 16 + lk * 4;
            const long rb = (long)(rg >> 11) * ((long)N * L_) + (rg & (L_ - 1));
#pragma unroll
            for (int n = 0; n < 4; ++n) {
                const int c = bn + wc * 64 + n * 16 + lr;
                u16x4 v;
#pragma unroll
                for (int g = 0; g < 4; ++g) v[g] = (unsigned short)f2h_bits(acc[m][n][g]);
                *(u16x4*)&C[rb + (long)c * L_] = v;
            }
        }
    }
}

// fp32 -> fp16 bit pattern, 8 elems/thread
__global__ __launch_bounds__(256) void cvt_f32_f16_k(
    const float* __restrict__ in, short* __restrict__ out, int n8)
{
    int i = blockIdx.x * 256 + threadIdx.x;
    if (i < n8) {
        float4 a = ((const float4*)in)[2 * i];
        float4 b = ((const float4*)in)[2 * i + 1];
        *(s16x8*)&out[i * 8] = cvt8h(a, b);
    }
}

// in-place row softmax over rows of length 2048; one block (256 thr) per row.
// Also writes a normalized fp16 copy (for the PV GEMM's gload_lds A-path).
__global__ __launch_bounds__(256) void softmax_rows_k(
    float* __restrict__ S, short* __restrict__ S16)
{
    const long row = blockIdx.x;
    float* p = S + row * (long)L_;
    short* p16 = S16 + row * (long)L_;
    const int tid = threadIdx.x;

    float4 v0 = ((const float4*)p)[tid];
    float4 v1 = ((const float4*)p)[tid + 256];

    float m = fmaxf(fmaxf(fmaxf(v0.x, v0.y), fmaxf(v0.z, v0.w)),
                    fmaxf(fmaxf(v1.x, v1.y), fmaxf(v1.z, v1.w)));
#pragma unroll
    for (int o = 32; o > 0; o >>= 1) m = fmaxf(m, __shfl_xor(m, o, 64));

    __shared__ float wmax[4], wsum[4];
    if ((tid & 63) == 0) wmax[tid >> 6] = m;
    __syncthreads();
    m = fmaxf(fmaxf(wmax[0], wmax[1]), fmaxf(wmax[2], wmax[3]));

    v0.x = expf(v0.x - m); v0.y = expf(v0.y - m);
    v0.z = expf(v0.z - m); v0.w = expf(v0.w - m);
    v1.x = expf(v1.x - m); v1.y = expf(v1.y - m);
    v1.z = expf(v1.z - m); v1.w = expf(v1.w - m);

    float s = v0.x + v0.y + v0.z + v0.w + v1.x + v1.y + v1.z + v1.w;
#pragma unroll
    for (int o = 32; o > 0; o >>= 1) s += __shfl_xor(s, o, 64);
    if ((tid & 63) == 0) wsum[tid >> 6] = s;
    __syncthreads();
    s = wsum[0] + wsum[1] + wsum[2] + wsum[3];

    const float inv = 1.f / s;
    v0.x *= inv; v0.y *= inv; v0.z *= inv; v0.w *= inv;
    v1.x *= inv; v1.y *= inv; v1.z *= inv; v1.w *= inv;
    ((float4*)p)[tid] = v0;
    ((float4*)p)[tid + 256] = v1;

    union { _Float16 h[4]; u16x4 u; } h0, h1;
    h0.h[0] = (_Float16)v0.x; h0.h[1] = (_Float16)v0.y;
    h0.h[2] = (_Float16)v0.z; h0.h[3] = (_Float16)v0.w;
    h1.h[0] = (_Float16)v1.x; h1.h[1] = (_Float16)v1.y;
    h1.h[2] = (_Float16)v1.z; h1.h[3] = (_Float16)v1.w;
    ((u16x4*)p16)[tid] = h0.u;
    ((u16x4*)p16)[tid + 256] = h1.u;
}

extern "C" void kernel_launch(void* const* d_in, const int* in_sizes, int n_in,
                              void* d_out, int out_size, void* d_ws, size_t ws_size,
                              hipStream_t stream) {
    const float* Q   = (const float*)d_in[0];
    const float* K   = (const float*)d_in[1];
    const float* V   = (const float*)d_in[2];
    const float* W_Q = (const float*)d_in[3];
    const float* W_K = (const float*)d_in[4];
    const float* W_V = (const float*)d_in[5];
    const float* W_O = (const float*)d_in[6];
    const int* masked = (const int*)d_in[7];

    float* out  = (float*)d_out;                    // [4,2048,1024]
    float* attn = out + (size_t)B_ * L_ * D_;       // [4,2048,2048]

    // ws layout (shorts): 8MB weights | qh 16.8 | kh 16.8 | vT 16.8 | attn16 33.6
    short* wq = (short*)d_ws;
    short* wk = wq + (size_t)D_ * D_;
    short* wv = wk + (size_t)D_ * D_;
    short* wo = wv + (size_t)D_ * D_;
    short* qh = wo + (size_t)D_ * D_;               // [8192,1024] f16
    short* kh = qh + (size_t)B_ * L_ * D_;
    short* vT = kh + (size_t)B_ * L_ * D_;          // [4][1024][2048] f16
    short* attn16 = vT + (size_t)B_ * L_ * D_;      // [4][2048][2048] f16
    short* xh = qh;                                 // reuse after scores

    const long SLD = (long)L_ * D_;
    const long SLL = (long)L_ * L_;

    // 1) weights fp32 -> fp16
    const int n8 = D_ * D_ / 8;
    cvt_f32_f16_k<<<dim3(n8 / 256), 256, 0, stream>>>(W_Q, wq, n8);
    cvt_f32_f16_k<<<dim3(n8 / 256), 256, 0, stream>>>(W_K, wk, n8);
    cvt_f32_f16_k<<<dim3(n8 / 256), 256, 0, stream>>>(W_V, wv, n8);
    cvt_f32_f16_k<<<dim3(n8 / 256), 256, 0, stream>>>(W_O, wo, n8);

    // 2) projections (A = fp32 inputs, reg-staged convert)
    dim3 gproj(D_ / BN, (B_ * L_) / BM, 1);
    hgemm<1, 0><<<gproj, 256, 0, stream>>>(Q, wq, qh, B_ * L_, D_, D_, 0, 0, 0, 1.f, 0, masked);
    hgemm<1, 0><<<gproj, 256, 0, stream>>>(K, wk, kh, B_ * L_, D_, D_, 0, 0, 0, 1.f, 0, masked);
    hgemm<1, 1><<<gproj, 256, 0, stream>>>(V, wv, vT, B_ * L_, D_, D_, 0, 0, 0, 1.f, 0, masked);

    // 3) scores = q @ k^T / 8 -> fp32 into attn slot (+ faithful mask)
    dim3 gsc(L_ / BN, L_ / BM, B_);
    hgemm<0, 2><<<gsc, 256, 0, stream>>>(qh, kh, attn, L_, L_, D_, SLD, SLD, SLL,
                                         0.125f, 1, masked);

    // 4) softmax rows, in place (fp32) + fp16 copy for PV
    softmax_rows_k<<<dim3(B_ * L_), 256, 0, stream>>>(attn, attn16);

    // 5) x = attn16 @ v  (A fp16 via gload_lds; B = vT) -> f16 x
    dim3 gav(D_ / BN, L_ / BM, B_);
    hgemm<0, 0><<<gav, 256, 0, stream>>>(attn16, vT, xh, L_, D_, L_, SLL, SLD, SLD,
                                         1.f, 0, masked);

    // 6) out = x @ W_O^T -> fp32
    hgemm<0, 2><<<gproj, 256, 0, stream>>>(xh, wo, out, B_ * L_, D_, D_, 0, 0, 0,
                                           1.f, 0, masked);
}